// Round 1
// baseline (285.439 us; speedup 1.0000x reference)
//
#include <hip/hip_runtime.h>

// SPDnet autoencoder, collapsed analytically:
//   out_b = D (E x_b E^T - EPS*I16) D^T + EPS*I128
// where E = Wenc2*Wenc1*Wenc0 (16x128), D = Wdec2*Wdec1*Wdec0 (128x16).
// Valid because: encoder ReEigs are no-ops (lambda_min >= 0.01 by interlacing),
// LogEig->ExpEig->ReEig is the identity, and decoder ReEigs clamp exactly the
// rank-deficient null space: reeig(W X W^T) = W X W^T + EPS*(I - W W^T) when
// all eig(X) >= EPS and W has orthonormal columns.

#define SPD_EPS 1e-4f

// ---------------- setup: build E (16x128) and D (128x16) in workspace -------
__global__ __launch_bounds__(256) void setup_ED(
    const float* __restrict__ wenc0,  // 64x128
    const float* __restrict__ wenc1,  // 32x64
    const float* __restrict__ wenc2,  // 16x32
    const float* __restrict__ wdec0,  // 32x16
    const float* __restrict__ wdec1,  // 64x32
    const float* __restrict__ wdec2,  // 128x64
    float* __restrict__ wsE,          // out: 16x128
    float* __restrict__ wsD)          // out: 128x16
{
    __shared__ float e1[16 * 64];   // Wenc2 @ Wenc1
    __shared__ float d1[64 * 16];   // Wdec1 @ Wdec0
    const int t = threadIdx.x;

    // e1 = Wenc2(16x32) @ Wenc1(32x64)
    for (int r = 0; r < 4; ++r) {
        int o = t + 256 * r;
        int i = o >> 6, j = o & 63;
        float acc = 0.f;
        for (int k = 0; k < 32; ++k) acc += wenc2[i * 32 + k] * wenc1[k * 64 + j];
        e1[o] = acc;
    }
    // d1 = Wdec1(64x32) @ Wdec0(32x16)
    for (int r = 0; r < 4; ++r) {
        int o = t + 256 * r;
        int p = o >> 4, m = o & 15;
        float acc = 0.f;
        for (int k = 0; k < 32; ++k) acc += wdec1[p * 32 + k] * wdec0[k * 16 + m];
        d1[o] = acc;
    }
    __syncthreads();
    // E = e1(16x64) @ Wenc0(64x128)
    for (int r = 0; r < 8; ++r) {
        int o = t + 256 * r;
        int i = o >> 7, j = o & 127;
        float acc = 0.f;
        for (int k = 0; k < 64; ++k) acc += e1[i * 64 + k] * wenc0[k * 128 + j];
        wsE[o] = acc;
    }
    // D = Wdec2(128x64) @ d1(64x16)
    for (int r = 0; r < 8; ++r) {
        int o = t + 256 * r;
        int p = o >> 4, m = o & 15;
        float acc = 0.f;
        for (int k = 0; k < 64; ++k) acc += wdec2[p * 64 + k] * d1[k * 16 + m];
        wsD[o] = acc;
    }
}

// ---------------- main: one block per batch element -------------------------
// LDS layout (floats), total 8672 floats = 33.875 KB -> 4 blocks/CU:
//   Esh : [0, 2064)      16 rows, stride 129 (pad kills 128-stride conflicts)
//   t1  : [2064, 4128)   16 rows, stride 129
//   Dt  : [4128, 6240)   D^T: 16 rows x 128 cols, stride 132 (16B-aligned f4)
//   rgA : [6240, 8672)   union { xbuf[16*128]=2048 | s[256] + u[128*17]=2176 }
__global__ __launch_bounds__(256) void spdnet_main(
    const float* __restrict__ x,    // B x 128 x 128
    const float* __restrict__ wsE,  // 16x128
    const float* __restrict__ wsD,  // 128x16
    float* __restrict__ out)        // B x 128 x 128
{
    __shared__ __align__(16) float smem[8672];
    float* Esh = smem;              // stride 129
    float* t1  = smem + 2064;       // stride 129
    float* Dt  = smem + 4128;       // stride 132
    float* rgA = smem + 6240;
    float* xbuf = rgA;              // 16x128 chunk of x
    float* s    = rgA;              // 16x16  (after xbuf is dead)
    float* u    = rgA + 256;        // 128x17

    const int t = threadIdx.x;
    const int b = blockIdx.x;
    const float* xb = x + (size_t)b * 16384;
    float* ob = out + (size_t)b * 16384;

    // load E (padded) and D (transposed, padded)
    for (int r = 0; r < 8; ++r) {
        int o = t + 256 * r;
        Esh[(o >> 7) * 129 + (o & 127)] = wsE[o];
        Dt[(o & 15) * 132 + (o >> 4)] = wsD[o];
    }

    // ---- stage 1: t1 = E @ x_b (16x128) ----
    // thread: column j = t&127; half h = t>>7 owns output rows [8h, 8h+8)
    const int j = t & 127;
    const int h = t >> 7;
    float acc[8];
#pragma unroll
    for (int ii = 0; ii < 8; ++ii) acc[ii] = 0.f;

    for (int c = 0; c < 8; ++c) {           // 8 chunks of 16 rows
        __syncthreads();                     // xbuf (and Esh on c=0) ready-guard
        const float4* src = (const float4*)(xb + c * 2048);
        float4* dst = (float4*)xbuf;
        dst[t]       = src[t];
        dst[t + 256] = src[t + 256];
        __syncthreads();
#pragma unroll
        for (int kk = 0; kk < 16; ++kk) {
            float xv = xbuf[kk * 128 + j];
            int kg = c * 16 + kk;
#pragma unroll
            for (int ii = 0; ii < 8; ++ii)
                acc[ii] += Esh[(8 * h + ii) * 129 + kg] * xv;
        }
    }
#pragma unroll
    for (int ii = 0; ii < 8; ++ii) t1[(8 * h + ii) * 129 + j] = acc[ii];
    __syncthreads();   // t1 complete; all xbuf reads done -> rgA reusable

    // ---- stage 2: s = t1 @ E^T - EPS*I (16x16) ----
    {
        int i = t >> 4, m = t & 15;
        float accs = 0.f;
        for (int jj = 0; jj < 128; ++jj)
            accs += t1[i * 129 + jj] * Esh[m * 129 + jj];
        if (i == m) accs -= SPD_EPS;
        s[t] = accs;                        // s[i*16+m]
    }
    __syncthreads();

    // ---- stage 3: u = D @ s (128x16) ----
    {
        int p = t & 127;                    // half h owns cols [8h, 8h+8)
        float accu[8];
#pragma unroll
        for (int r = 0; r < 8; ++r) accu[r] = 0.f;
        for (int i = 0; i < 16; ++i) {
            float dv = Dt[i * 132 + p];
#pragma unroll
            for (int r = 0; r < 8; ++r)
                accu[r] += dv * s[i * 16 + 8 * h + r];
        }
#pragma unroll
        for (int r = 0; r < 8; ++r) u[p * 17 + 8 * h + r] = accu[r];
    }
    __syncthreads();

    // ---- stage 4: out = u @ D^T + EPS*I, float4 stores ----
    {
        const int q4 = (t & 31) * 4;        // column quad
        const int pw = t >> 5;              // 0..7
        for (int it = 0; it < 16; ++it) {
            int p = it * 8 + pw;
            float4 a4 = make_float4(0.f, 0.f, 0.f, 0.f);
#pragma unroll
            for (int m = 0; m < 16; ++m) {
                float uv = u[p * 17 + m];
                float4 d4 = *(const float4*)&Dt[m * 132 + q4];
                a4.x += uv * d4.x;
                a4.y += uv * d4.y;
                a4.z += uv * d4.z;
                a4.w += uv * d4.w;
            }
            int d = p - q4;
            if (d >= 0 && d < 4) (&a4.x)[d] += SPD_EPS;
            *(float4*)(ob + p * 128 + q4) = a4;
        }
    }
}

extern "C" void kernel_launch(void* const* d_in, const int* in_sizes, int n_in,
                              void* d_out, int out_size, void* d_ws, size_t ws_size,
                              hipStream_t stream) {
    const float* x     = (const float*)d_in[0];
    const float* wenc0 = (const float*)d_in[1];
    const float* wenc1 = (const float*)d_in[2];
    const float* wenc2 = (const float*)d_in[3];
    const float* wdec0 = (const float*)d_in[4];
    const float* wdec1 = (const float*)d_in[5];
    const float* wdec2 = (const float*)d_in[6];
    float* out = (float*)d_out;

    float* wsE = (float*)d_ws;          // 2048 floats
    float* wsD = wsE + 2048;            // 2048 floats

    const int B = in_sizes[0] / 16384;  // 2048

    setup_ED<<<1, 256, 0, stream>>>(wenc0, wenc1, wenc2, wdec0, wdec1, wdec2,
                                    wsE, wsD);
    spdnet_main<<<B, 256, 0, stream>>>(x, wsE, wsD, out);
}